// Round 1
// baseline (210.685 us; speedup 1.0000x reference)
//
#include <hip/hip_runtime.h>

#define VMF_D 512

// ---------------------------------------------------------------------------
// Prep kernel: one block of 512 threads.
//   ws[0..511] = mu = mu_unnorm / ||mu_unnorm||
//   ws[512]    = kappa = exp(logkappa) + 1e-6
//   ws[513]    = logC  = D*(-0.5*log(2pi)) + s*log(kappa) - log I_s(kappa)
// log I_s(kappa) via ascending series, parallel logsumexp over 512 terms,
// all in double precision (magnitudes ~1e3; fp64 kills cancellation risk).
// ---------------------------------------------------------------------------
__global__ void vmf_prep(const float* __restrict__ mu_unnorm,
                         const float* __restrict__ logkappa,
                         float* __restrict__ ws) {
    __shared__ double dred[8];
    __shared__ float  fred[8];
    const int tid  = threadIdx.x;       // 0..511
    const int lane = tid & 63;
    const int wid  = tid >> 6;

    // --- normalize mu (fp32, matches reference) ---
    float v  = mu_unnorm[tid];
    float sq = v * v;
    #pragma unroll
    for (int off = 32; off; off >>= 1) sq += __shfl_xor(sq, off);
    if (lane == 0) fred[wid] = sq;
    __syncthreads();
    float norm2 = 0.f;
    #pragma unroll
    for (int i = 0; i < 8; ++i) norm2 += fred[i];
    ws[tid] = v / sqrtf(norm2);

    // --- series term k = tid ---
    const double kappa = exp((double)logkappa[0]) + 1e-6;
    const double s     = 0.5 * VMF_D - 1.0;        // 255
    const double lh    = log(kappa * 0.5);
    double lt = (2.0 * tid + s) * lh
              - lgamma((double)tid + 1.0)
              - lgamma((double)tid + s + 1.0);

    // --- block logsumexp (max, then sum of exp) ---
    double m = lt;
    #pragma unroll
    for (int off = 32; off; off >>= 1) m = fmax(m, __shfl_xor(m, off));
    if (lane == 0) dred[wid] = m;
    __syncthreads();
    double mall = dred[0];
    #pragma unroll
    for (int i = 1; i < 8; ++i) mall = fmax(mall, dred[i]);

    double e = exp(lt - mall);
    #pragma unroll
    for (int off = 32; off; off >>= 1) e += __shfl_xor(e, off);
    __syncthreads();                 // done reading dred (max phase)
    if (lane == 0) dred[wid] = e;
    __syncthreads();

    if (tid == 0) {
        double ssum = 0.0;
        for (int i = 0; i < 8; ++i) ssum += dred[i];
        double logI = mall + log(ssum);
        double logC = (double)VMF_D * -0.91893853320467274178 /* -0.5*log(2pi) */
                    + s * log(kappa) - logI;
        ws[VMF_D]     = (float)kappa;
        ws[VMF_D + 1] = (float)logC;
    }
}

// ---------------------------------------------------------------------------
// Main kernel: one 64-lane wave per row.  Lane l loads x[row][4l..4l+3] and
// x[row][256+4l..256+4l+3] (two coalesced 1 KiB wave transactions), FMAs
// against register-resident mu fragments, 6-step shfl_xor reduce, lane 0
// writes kappa*dot + logC.  Grid-stride over rows.
// ---------------------------------------------------------------------------
__global__ void __launch_bounds__(256)
vmf_main(const float* __restrict__ x,
         const float* __restrict__ ws,
         float* __restrict__ out,
         int n) {
    const int lane   = threadIdx.x & 63;
    const int wave   = (blockIdx.x * blockDim.x + threadIdx.x) >> 6;
    const int nwaves = (gridDim.x * blockDim.x) >> 6;

    const float4 m0 = *reinterpret_cast<const float4*>(ws + lane * 4);
    const float4 m1 = *reinterpret_cast<const float4*>(ws + 256 + lane * 4);
    const float kappa = ws[VMF_D];
    const float logC  = ws[VMF_D + 1];

    for (int row = wave; row < n; row += nwaves) {
        const float* xr = x + (size_t)row * VMF_D;
        const float4 a0 = *reinterpret_cast<const float4*>(xr + lane * 4);
        const float4 a1 = *reinterpret_cast<const float4*>(xr + 256 + lane * 4);
        float p = a0.x * m0.x + a0.y * m0.y + a0.z * m0.z + a0.w * m0.w
                + a1.x * m1.x + a1.y * m1.y + a1.z * m1.z + a1.w * m1.w;
        #pragma unroll
        for (int off = 32; off; off >>= 1) p += __shfl_xor(p, off);
        if (lane == 0) out[row] = fmaf(kappa, p, logC);
    }
}

extern "C" void kernel_launch(void* const* d_in, const int* in_sizes, int n_in,
                              void* d_out, int out_size, void* d_ws, size_t ws_size,
                              hipStream_t stream) {
    const float* x         = (const float*)d_in[0];
    const float* mu_unnorm = (const float*)d_in[1];
    const float* logkappa  = (const float*)d_in[2];
    float* out = (float*)d_out;
    float* ws  = (float*)d_ws;
    const int n = in_sizes[0] / VMF_D;   // 524288 rows

    vmf_prep<<<1, VMF_D, 0, stream>>>(mu_unnorm, logkappa, ws);
    vmf_main<<<2048, 256, 0, stream>>>(x, ws, out, n);
}

// Round 3
// 186.456 us; speedup vs baseline: 1.1299x; 1.1299x over previous
//
#include <hip/hip_runtime.h>

#define VMF_D 512

typedef float f32x4 __attribute__((ext_vector_type(4)));

// ---------------------------------------------------------------------------
// Prep kernel: one block of 512 threads.
//   ws[0..511] = mu = mu_unnorm / ||mu_unnorm||
//   ws[512]    = kappa = exp(logkappa) + 1e-6
//   ws[513]    = logC  = D*(-0.5*log(2pi)) + s*log(kappa) - log I_s(kappa)
// log I_s(kappa) via ascending series, parallel logsumexp over 512 terms,
// all in double precision (magnitudes ~1e3; fp64 kills cancellation risk).
// ---------------------------------------------------------------------------
__global__ void vmf_prep(const float* __restrict__ mu_unnorm,
                         const float* __restrict__ logkappa,
                         float* __restrict__ ws) {
    __shared__ double dred[8];
    __shared__ float  fred[8];
    const int tid  = threadIdx.x;       // 0..511
    const int lane = tid & 63;
    const int wid  = tid >> 6;

    // --- normalize mu (fp32, matches reference) ---
    float v  = mu_unnorm[tid];
    float sq = v * v;
    #pragma unroll
    for (int off = 32; off; off >>= 1) sq += __shfl_xor(sq, off);
    if (lane == 0) fred[wid] = sq;
    __syncthreads();
    float norm2 = 0.f;
    #pragma unroll
    for (int i = 0; i < 8; ++i) norm2 += fred[i];
    ws[tid] = v / sqrtf(norm2);

    // --- series term k = tid ---
    const double kappa = exp((double)logkappa[0]) + 1e-6;
    const double s     = 0.5 * VMF_D - 1.0;        // 255
    const double lh    = log(kappa * 0.5);
    double lt = (2.0 * tid + s) * lh
              - lgamma((double)tid + 1.0)
              - lgamma((double)tid + s + 1.0);

    // --- block logsumexp (max, then sum of exp) ---
    double m = lt;
    #pragma unroll
    for (int off = 32; off; off >>= 1) m = fmax(m, __shfl_xor(m, off));
    if (lane == 0) dred[wid] = m;
    __syncthreads();
    double mall = dred[0];
    #pragma unroll
    for (int i = 1; i < 8; ++i) mall = fmax(mall, dred[i]);

    double e = exp(lt - mall);
    #pragma unroll
    for (int off = 32; off; off >>= 1) e += __shfl_xor(e, off);
    __syncthreads();                 // done reading dred (max phase)
    if (lane == 0) dred[wid] = e;
    __syncthreads();

    if (tid == 0) {
        double ssum = 0.0;
        for (int i = 0; i < 8; ++i) ssum += dred[i];
        double logI = mall + log(ssum);
        double logC = (double)VMF_D * -0.91893853320467274178 /* -0.5*log(2pi) */
                    + s * log(kappa) - logI;
        ws[VMF_D]     = (float)kappa;
        ws[VMF_D + 1] = (float)logC;
    }
}

// ---------------------------------------------------------------------------
// Main kernel: one 64-lane wave per 4-ROW GROUP.
//   - 8 independent nontemporal f32x4 loads per iteration (4 rows x 2) ->
//     4x the in-flight memory per wave vs the 1-row version.
//   - 4 independent shuffle-reduce chains pipeline through DS/VALU.
//   - lane 0 stores one coalesced f32x4 (4 consecutive rows' results).
// Grid-stride over groups.  N=524288 is divisible by 4; a scalar tail
// loop on the last wave guards the general case.
// ---------------------------------------------------------------------------
__global__ void __launch_bounds__(256, 8)
vmf_main(const float* __restrict__ x,
         const float* __restrict__ ws,
         float* __restrict__ out,
         int n) {
    const int lane   = threadIdx.x & 63;
    const int wave   = (blockIdx.x * blockDim.x + threadIdx.x) >> 6;
    const int nwaves = (gridDim.x * blockDim.x) >> 6;

    const f32x4 m0 = *reinterpret_cast<const f32x4*>(ws + lane * 4);
    const f32x4 m1 = *reinterpret_cast<const f32x4*>(ws + 256 + lane * 4);
    const float kappa = ws[VMF_D];
    const float logC  = ws[VMF_D + 1];

    const int ngroups = n >> 2;
    for (int g = wave; g < ngroups; g += nwaves) {
        const float* xr = x + ((size_t)g << 11);   // 4 rows * 512 floats
        f32x4 a0[4], a1[4];
        #pragma unroll
        for (int r = 0; r < 4; ++r) {
            a0[r] = __builtin_nontemporal_load(
                        reinterpret_cast<const f32x4*>(xr + r * VMF_D + lane * 4));
            a1[r] = __builtin_nontemporal_load(
                        reinterpret_cast<const f32x4*>(xr + r * VMF_D + 256 + lane * 4));
        }
        float p[4];
        #pragma unroll
        for (int r = 0; r < 4; ++r) {
            p[r] = a0[r].x * m0.x + a0[r].y * m0.y + a0[r].z * m0.z + a0[r].w * m0.w
                 + a1[r].x * m1.x + a1[r].y * m1.y + a1[r].z * m1.z + a1[r].w * m1.w;
        }
        #pragma unroll
        for (int off = 32; off; off >>= 1) {
            #pragma unroll
            for (int r = 0; r < 4; ++r) p[r] += __shfl_xor(p[r], off);
        }
        if (lane == 0) {
            f32x4 o;
            o.x = fmaf(kappa, p[0], logC);
            o.y = fmaf(kappa, p[1], logC);
            o.z = fmaf(kappa, p[2], logC);
            o.w = fmaf(kappa, p[3], logC);
            __builtin_nontemporal_store(o, reinterpret_cast<f32x4*>(out + (g << 2)));
        }
    }

    // scalar tail for n % 4 != 0 (not hit for N=524288)
    const int tail_start = ngroups << 2;
    if (wave == nwaves - 1) {
        for (int row = tail_start; row < n; ++row) {
            const float* xr = x + (size_t)row * VMF_D;
            const f32x4 a0 = *reinterpret_cast<const f32x4*>(xr + lane * 4);
            const f32x4 a1 = *reinterpret_cast<const f32x4*>(xr + 256 + lane * 4);
            float p = a0.x * m0.x + a0.y * m0.y + a0.z * m0.z + a0.w * m0.w
                    + a1.x * m1.x + a1.y * m1.y + a1.z * m1.z + a1.w * m1.w;
            #pragma unroll
            for (int off = 32; off; off >>= 1) p += __shfl_xor(p, off);
            if (lane == 0) out[row] = fmaf(kappa, p, logC);
        }
    }
}

extern "C" void kernel_launch(void* const* d_in, const int* in_sizes, int n_in,
                              void* d_out, int out_size, void* d_ws, size_t ws_size,
                              hipStream_t stream) {
    const float* x         = (const float*)d_in[0];
    const float* mu_unnorm = (const float*)d_in[1];
    const float* logkappa  = (const float*)d_in[2];
    float* out = (float*)d_out;
    float* ws  = (float*)d_ws;
    const int n = in_sizes[0] / VMF_D;   // 524288 rows

    vmf_prep<<<1, VMF_D, 0, stream>>>(mu_unnorm, logkappa, ws);
    vmf_main<<<4096, 256, 0, stream>>>(x, ws, out, n);
}

// Round 4
// 178.548 us; speedup vs baseline: 1.1800x; 1.0443x over previous
//
#include <hip/hip_runtime.h>

#define VMF_D 512

typedef float f32x4 __attribute__((ext_vector_type(4)));

// ---------------------------------------------------------------------------
// Prep kernel: one block of 512 threads.
//   ws[0..511] = mu = mu_unnorm / ||mu_unnorm||
//   ws[512]    = kappa = exp(logkappa) + 1e-6
//   ws[513]    = logC  = D*(-0.5*log(2pi)) + s*log(kappa) - log I_s(kappa)
// log I_s(kappa) via ascending series, parallel logsumexp over 512 terms,
// all in double precision (magnitudes ~1e3; fp64 kills cancellation risk).
// ---------------------------------------------------------------------------
__global__ void vmf_prep(const float* __restrict__ mu_unnorm,
                         const float* __restrict__ logkappa,
                         float* __restrict__ ws) {
    __shared__ double dred[8];
    __shared__ float  fred[8];
    const int tid  = threadIdx.x;       // 0..511
    const int lane = tid & 63;
    const int wid  = tid >> 6;

    // --- normalize mu (fp32, matches reference) ---
    float v  = mu_unnorm[tid];
    float sq = v * v;
    #pragma unroll
    for (int off = 32; off; off >>= 1) sq += __shfl_xor(sq, off);
    if (lane == 0) fred[wid] = sq;
    __syncthreads();
    float norm2 = 0.f;
    #pragma unroll
    for (int i = 0; i < 8; ++i) norm2 += fred[i];
    ws[tid] = v / sqrtf(norm2);

    // --- series term k = tid ---
    const double kappa = exp((double)logkappa[0]) + 1e-6;
    const double s     = 0.5 * VMF_D - 1.0;        // 255
    const double lh    = log(kappa * 0.5);
    double lt = (2.0 * tid + s) * lh
              - lgamma((double)tid + 1.0)
              - lgamma((double)tid + s + 1.0);

    // --- block logsumexp (max, then sum of exp) ---
    double m = lt;
    #pragma unroll
    for (int off = 32; off; off >>= 1) m = fmax(m, __shfl_xor(m, off));
    if (lane == 0) dred[wid] = m;
    __syncthreads();
    double mall = dred[0];
    #pragma unroll
    for (int i = 1; i < 8; ++i) mall = fmax(mall, dred[i]);

    double e = exp(lt - mall);
    #pragma unroll
    for (int off = 32; off; off >>= 1) e += __shfl_xor(e, off);
    __syncthreads();                 // done reading dred (max phase)
    if (lane == 0) dred[wid] = e;
    __syncthreads();

    if (tid == 0) {
        double ssum = 0.0;
        for (int i = 0; i < 8; ++i) ssum += dred[i];
        double logI = mall + log(ssum);
        double logC = (double)VMF_D * -0.91893853320467274178 /* -0.5*log(2pi) */
                    + s * log(kappa) - logI;
        ws[VMF_D]     = (float)kappa;
        ws[VMF_D + 1] = (float)logC;
    }
}

// ---------------------------------------------------------------------------
// Main kernel: one 64-lane wave per 4-ROW GROUP, register double-buffered.
//   - 8 nontemporal f32x4 loads per group (4 rows x 2).
//   - Next group's loads are ISSUED before the current group's shuffle
//     reduction, so the VMEM queue never drains at iteration boundaries.
//   - Named A/B buffers, 2-step ping-pong (static indexing - no scratch).
//   - lane 0 stores one coalesced f32x4 (4 consecutive rows' results).
// __launch_bounds__(256,4): ~90 VGPRs live (2x32 data + 8 mu + addr), the
// old (256,8)/64-VGPR cap would spill.
// ---------------------------------------------------------------------------
#define LOADG(BUF0, BUF1, gidx)                                                  \
    {                                                                            \
        const float* xr_ = x + ((size_t)(gidx) << 11); /* 4 rows * 512 */        \
        _Pragma("unroll")                                                        \
        for (int r = 0; r < 4; ++r) {                                            \
            BUF0[r] = __builtin_nontemporal_load(                                \
                reinterpret_cast<const f32x4*>(xr_ + r * VMF_D + lane * 4));     \
            BUF1[r] = __builtin_nontemporal_load(                                \
                reinterpret_cast<const f32x4*>(xr_ + r * VMF_D + 256 + lane * 4)); \
        }                                                                        \
    }

#define COMPUTE(BUF0, BUF1, gidx)                                                \
    {                                                                            \
        float p_[4];                                                             \
        _Pragma("unroll")                                                        \
        for (int r = 0; r < 4; ++r)                                              \
            p_[r] = BUF0[r].x * m0.x + BUF0[r].y * m0.y + BUF0[r].z * m0.z       \
                  + BUF0[r].w * m0.w                                             \
                  + BUF1[r].x * m1.x + BUF1[r].y * m1.y + BUF1[r].z * m1.z       \
                  + BUF1[r].w * m1.w;                                            \
        _Pragma("unroll")                                                        \
        for (int off_ = 32; off_; off_ >>= 1) {                                  \
            _Pragma("unroll")                                                    \
            for (int r = 0; r < 4; ++r) p_[r] += __shfl_xor(p_[r], off_);        \
        }                                                                        \
        if (lane == 0) {                                                         \
            f32x4 o_;                                                            \
            o_.x = fmaf(kappa, p_[0], logC);                                     \
            o_.y = fmaf(kappa, p_[1], logC);                                     \
            o_.z = fmaf(kappa, p_[2], logC);                                     \
            o_.w = fmaf(kappa, p_[3], logC);                                     \
            __builtin_nontemporal_store(                                         \
                o_, reinterpret_cast<f32x4*>(out + ((size_t)(gidx) << 2)));      \
        }                                                                        \
    }

__global__ void __launch_bounds__(256, 4)
vmf_main(const float* __restrict__ x,
         const float* __restrict__ ws,
         float* __restrict__ out,
         int n) {
    const int lane   = threadIdx.x & 63;
    const int wave   = (blockIdx.x * blockDim.x + threadIdx.x) >> 6;
    const int nwaves = (gridDim.x * blockDim.x) >> 6;

    const f32x4 m0 = *reinterpret_cast<const f32x4*>(ws + lane * 4);
    const f32x4 m1 = *reinterpret_cast<const f32x4*>(ws + 256 + lane * 4);
    const float kappa = ws[VMF_D];
    const float logC  = ws[VMF_D + 1];

    const int ngroups = n >> 2;
    f32x4 A0[4], A1[4], B0[4], B1[4];

    int g = wave;
    if (g < ngroups) {
        LOADG(A0, A1, g);
        while (true) {
            const int g1 = g + nwaves;
            if (g1 < ngroups) LOADG(B0, B1, g1);       // prefetch next
            COMPUTE(A0, A1, g);                        // reduce current
            if (g1 >= ngroups) break;
            const int g2 = g1 + nwaves;
            if (g2 < ngroups) LOADG(A0, A1, g2);       // prefetch next-next
            COMPUTE(B0, B1, g1);
            if (g2 >= ngroups) break;
            g = g2;
        }
    }

    // scalar tail for n % 4 != 0 (not hit for N=524288)
    const int tail_start = ngroups << 2;
    if (wave == nwaves - 1) {
        for (int row = tail_start; row < n; ++row) {
            const float* xr = x + (size_t)row * VMF_D;
            const f32x4 a0 = *reinterpret_cast<const f32x4*>(xr + lane * 4);
            const f32x4 a1 = *reinterpret_cast<const f32x4*>(xr + 256 + lane * 4);
            float p = a0.x * m0.x + a0.y * m0.y + a0.z * m0.z + a0.w * m0.w
                    + a1.x * m1.x + a1.y * m1.y + a1.z * m1.z + a1.w * m1.w;
            #pragma unroll
            for (int off = 32; off; off >>= 1) p += __shfl_xor(p, off);
            if (lane == 0) out[row] = fmaf(kappa, p, logC);
        }
    }
}

extern "C" void kernel_launch(void* const* d_in, const int* in_sizes, int n_in,
                              void* d_out, int out_size, void* d_ws, size_t ws_size,
                              hipStream_t stream) {
    const float* x         = (const float*)d_in[0];
    const float* mu_unnorm = (const float*)d_in[1];
    const float* logkappa  = (const float*)d_in[2];
    float* out = (float*)d_out;
    float* ws  = (float*)d_ws;
    const int n = in_sizes[0] / VMF_D;   // 524288 rows

    vmf_prep<<<1, VMF_D, 0, stream>>>(mu_unnorm, logkappa, ws);
    vmf_main<<<4096, 256, 0, stream>>>(x, ws, out, n);
}